// Round 2
// baseline (469.407 us; speedup 1.0000x reference)
//
#include <hip/hip_runtime.h>
#include <cmath>

// Problem constants
#define BB 64
#define RR 4608
#define CC 32
#define INN 8
#define OUTT 16

constexpr int RSTAGE = 8;               // r rows per staging sub-chunk
constexpr int KCH    = 3;               // sub-chunks per block
constexpr int RCB    = RSTAGE * KCH;    // 24 r per block
constexpr int NCHUNK = RR / RCB;        // 192
constexpr int CT     = 4;               // c per block (one wave each)
constexpr int XSTR   = RSTAGE * INN + 4; // 68 floats: pad -> 8-group bank spread

// Flash-style pass with double-buffered x staging.
// For each (b,c,r): uh[o] = sum_i x[b,r,i]*W[r,c,i,o] (W via wave-uniform s_loads),
// logit = uh.V, p = exp(logit), accumulate z += p, sacc[o] += p*uh[o].
__global__ __launch_bounds__(256, 4)
void caps_pass(const float* __restrict__ x, const float* __restrict__ W,
               const float* __restrict__ V, float* __restrict__ pz,
               float* __restrict__ ps)
{
    __shared__ float xs[2][BB][XSTR];    // 2 x 17.4 KB = 34.8 KB

    const int tid  = threadIdx.x;
    const int lane = tid & 63;           // = b
    const int wv   = tid >> 6;           // 0..3
    const int ch   = blockIdx.x;         // 0..191
    const int r0   = ch * RCB;
    const int c    = __builtin_amdgcn_readfirstlane(blockIdx.y * CT + wv);

    const int bq  = tid >> 4;            // 0..15 (b sub-row per j)
    const int pos = tid & 15;            // float4 position within 64-float b-row

    float4 st[4];

    // Stage sub-chunk starting at global row rs into registers (coalesced).
    auto load_stage = [&](int rs) {
#pragma unroll
        for (int j = 0; j < 4; ++j) {
            int b = j * 16 + bq;
            st[j] = *reinterpret_cast<const float4*>(
                x + ((size_t)b * RR + rs) * INN + pos * 4);
        }
    };
    auto write_stage = [&](int buf) {
#pragma unroll
        for (int j = 0; j < 4; ++j) {
            int b = j * 16 + bq;
            *reinterpret_cast<float4*>(&xs[buf][b][pos * 4]) = st[j];
        }
    };

    // prologue: stage sub-chunk 0
    load_stage(r0);
    write_stage(0);

    // per-thread cumulative V for (b=lane, c)
    float Vr[OUTT];
    {
        const float* vp = V + ((size_t)c * BB + lane) * OUTT;
#pragma unroll
        for (int o = 0; o < OUTT; ++o) Vr[o] = vp[o];
    }

    float z = 0.f;
    float sacc[OUTT];
#pragma unroll
    for (int o = 0; o < OUTT; ++o) sacc[o] = 0.f;

    __syncthreads();

    for (int k = 0; k < KCH; ++k) {
        const int cur = k & 1;

        // T14 async split: issue next sub-chunk's global loads now;
        // their latency hides under this sub-chunk's compute.
        if (k + 1 < KCH) load_stage(r0 + (k + 1) * RSTAGE);

        const float* Wr = W + (((size_t)(r0 + k * RSTAGE) * CC + c) * INN) * OUTT;

#pragma unroll 2
        for (int r = 0; r < RSTAGE; ++r) {
            float4 xA = *reinterpret_cast<const float4*>(&xs[cur][lane][r * INN]);
            float4 xB = *reinterpret_cast<const float4*>(&xs[cur][lane][r * INN + 4]);

            float uh[OUTT];
#pragma unroll
            for (int o = 0; o < OUTT; ++o) uh[o] = 0.f;
#pragma unroll
            for (int o = 0; o < OUTT; ++o) uh[o] = fmaf(xA.x, Wr[0 * OUTT + o], uh[o]);
#pragma unroll
            for (int o = 0; o < OUTT; ++o) uh[o] = fmaf(xA.y, Wr[1 * OUTT + o], uh[o]);
#pragma unroll
            for (int o = 0; o < OUTT; ++o) uh[o] = fmaf(xA.z, Wr[2 * OUTT + o], uh[o]);
#pragma unroll
            for (int o = 0; o < OUTT; ++o) uh[o] = fmaf(xA.w, Wr[3 * OUTT + o], uh[o]);
#pragma unroll
            for (int o = 0; o < OUTT; ++o) uh[o] = fmaf(xB.x, Wr[4 * OUTT + o], uh[o]);
#pragma unroll
            for (int o = 0; o < OUTT; ++o) uh[o] = fmaf(xB.y, Wr[5 * OUTT + o], uh[o]);
#pragma unroll
            for (int o = 0; o < OUTT; ++o) uh[o] = fmaf(xB.z, Wr[6 * OUTT + o], uh[o]);
#pragma unroll
            for (int o = 0; o < OUTT; ++o) uh[o] = fmaf(xB.w, Wr[7 * OUTT + o], uh[o]);

            float logit = 0.f;
#pragma unroll
            for (int o = 0; o < OUTT; ++o) logit = fmaf(uh[o], Vr[o], logit);

            float p = __expf(logit);     // V=0 on iter0 -> uniform routing
            z += p;
#pragma unroll
            for (int o = 0; o < OUTT; ++o) sacc[o] = fmaf(p, uh[o], sacc[o]);

            Wr += CC * INN * OUTT;       // next r row (stride 32*128 floats)
        }

        if (k + 1 < KCH) write_stage(cur ^ 1);  // other buffer: safe vs readers of cur
        __syncthreads();
    }

    // write partials
    const size_t base = ((size_t)ch * CC + c) * BB + lane;
    pz[base] = z;
    float* psp = ps + base * OUTT;
#pragma unroll
    for (int q = 0; q < OUTT / 4; ++q) {
        float4 v4 = make_float4(sacc[4 * q], sacc[4 * q + 1],
                                sacc[4 * q + 2], sacc[4 * q + 3]);
        *reinterpret_cast<float4*>(psp + 4 * q) = v4;
    }
}

// Combine partials over r-chunks, squash, accumulate V or emit output.
template <int LAST>
__global__ __launch_bounds__(256)
void caps_combine(const float* __restrict__ pz, const float* __restrict__ ps,
                  float* __restrict__ V, float* __restrict__ out)
{
    const int tid = blockIdx.x * 256 + threadIdx.x;  // 0..32767
    const int o  = tid & 15;
    const int bc = tid >> 4;        // 0..2047
    const int b  = bc & 63;
    const int c  = bc >> 6;

    float Z = 0.f, sv = 0.f;
#pragma unroll 4
    for (int chk = 0; chk < NCHUNK; ++chk) {
        const size_t base = ((size_t)chk * CC + c) * BB + b;
        Z  += pz[base];
        sv += ps[base * OUTT + o];
    }
    float st = sv / Z;              // s[b,c,o]

    float sq = st * st;
#pragma unroll
    for (int m = 1; m < 16; m <<= 1) sq += __shfl_xor(sq, m);
    float scale = (sq / (1.0f + sq)) / sqrtf(sq + 1e-8f);
    float v = st * scale;

    if (LAST) {
        out[((size_t)b * CC + c) * OUTT + o] = v;      // (B,C,OUT)
    } else {
        V[((size_t)c * BB + b) * OUTT + o] += v;       // cumulative logit vector
    }
}

extern "C" void kernel_launch(void* const* d_in, const int* in_sizes, int n_in,
                              void* d_out, int out_size, void* d_ws, size_t ws_size,
                              hipStream_t stream)
{
    const float* x = (const float*)d_in[0];   // (B,R,IN)
    const float* W = (const float*)d_in[1];   // (R,C,IN,OUT)
    float* out = (float*)d_out;               // (B,C,OUT)

    float* wsf = (float*)d_ws;
    float* V  = wsf;                                    // 32768 floats
    float* pz = wsf + (size_t)BB * CC * OUTT;           // NCHUNK*C*B
    float* ps = pz + (size_t)NCHUNK * CC * BB;          // NCHUNK*C*B*16

    hipMemsetAsync(V, 0, (size_t)BB * CC * OUTT * sizeof(float), stream);

    dim3 grid(NCHUNK, CC / CT);
    for (int it = 0; it < 3; ++it) {
        caps_pass<<<grid, 256, 0, stream>>>(x, W, V, pz, ps);
        if (it < 2)
            caps_combine<0><<<128, 256, 0, stream>>>(pz, ps, V, out);
        else
            caps_combine<1><<<128, 256, 0, stream>>>(pz, ps, V, out);
    }
}